// Round 1
// baseline (2185.166 us; speedup 1.0000x reference)
//
#include <hip/hip_runtime.h>
#include <cfloat>

#define B_    4
#define SNIP  8
#define CCH   256
#define HW    784
#define THW   6272      // SNIP*HW
#define BSZ   32
#define NROWS 25088     // B_*THW == BSZ*HW
#define TOPK  5

#define TR 128
#define TJ 64
#define KC 64

// ---------------------------------------------------------------- utilities
__device__ __forceinline__ void ins5(float key, int idx, float tv[TOPK], int ti[TOPK]) {
    // tv sorted descending; strict '>' keeps earliest-seen on ties
    if (key > tv[4]) {
        if (key > tv[2]) {
            if (key > tv[1]) {
                tv[4] = tv[3]; ti[4] = ti[3];
                tv[3] = tv[2]; ti[3] = ti[2];
                tv[2] = tv[1]; ti[2] = ti[1];
                if (key > tv[0]) { tv[1] = tv[0]; ti[1] = ti[0]; tv[0] = key; ti[0] = idx; }
                else             { tv[1] = key;  ti[1] = idx; }
            } else {
                tv[4] = tv[3]; ti[4] = ti[3];
                tv[3] = tv[2]; ti[3] = ti[2];
                tv[2] = key;   ti[2] = idx;
            }
        } else {
            if (key > tv[3]) { tv[4] = tv[3]; ti[4] = ti[3]; tv[3] = key; ti[3] = idx; }
            else             { tv[4] = key;  ti[4] = idx; }
        }
    }
}

// ------------------------------------------------- 1. x[bs][c][p] -> xs[b][t][c]
__global__ __launch_bounds__(256)
void transpose_kernel(const float* __restrict__ x, float* __restrict__ xs) {
    __shared__ float T[32][33];
    const int bs = blockIdx.x;               // 0..31
    const int p0 = blockIdx.y * 32;          // 25 tiles (784 -> pad)
    const int c0 = blockIdx.z * 32;          // 8 tiles
    const int tx = threadIdx.x & 31, ty = threadIdx.x >> 5;  // ty 0..7
    const int b = bs >> 3, f = bs & 7;
#pragma unroll
    for (int q = 0; q < 4; ++q) {
        const int c = c0 + ty + 8 * q;
        const int p = p0 + tx;
        if (p < HW) T[ty + 8 * q][tx] = x[((size_t)bs * CCH + c) * HW + p];
    }
    __syncthreads();
#pragma unroll
    for (int q = 0; q < 4; ++q) {
        const int p = p0 + ty + 8 * q;
        if (p < HW)
            xs[((size_t)((size_t)b * THW + (size_t)f * HW + p)) * CCH + c0 + tx] = T[tx][ty + 8 * q];
    }
}

// ------------------------------------------------- 2. per-row inverse norm
__global__ __launch_bounds__(256)
void rownorm_kernel(const float* __restrict__ xs, float* __restrict__ rinv) {
    const int tid = threadIdx.x;
    const int row = blockIdx.x * 4 + (tid >> 6);   // 6272 blocks * 4 rows = 25088
    const int lane = tid & 63;
    const float4 v = *(const float4*)(xs + (size_t)row * CCH + lane * 4);
    float s = v.x * v.x + v.y * v.y + v.z * v.z + v.w * v.w;
#pragma unroll
    for (int m = 32; m >= 1; m >>= 1) s += __shfl_xor(s, m, 64);
    if (lane == 0) rinv[row] = 1.0f / sqrtf(s);
}

// ------------------------------------------------- 3. fused gram + top-5
// grid (98, 4): 64-column block per wg, loop over all 6272 rows in 128-row tiles.
__global__ __launch_bounds__(256, 2)
void gram_topk_kernel(const float* __restrict__ xs, const float* __restrict__ rinv,
                      int* __restrict__ idx5) {
    __shared__ float smem[(TR + TJ) * KC];   // 48 KB
    float* As = smem;
    float* Bs = smem + TR * KC;

    const int tid = threadIdx.x;
    const int b   = blockIdx.y;
    const int j0  = blockIdx.x * TJ;
    const int rg  = tid >> 4;       // 0..15  -> 8 rows
    const int cg  = tid & 15;       // 0..15  -> 4 cols
    const int swa = rg & 7;
    const int swb = cg >> 1;
    const int sab16 = ((swa ^ swb) << 4);    // byte-offset XOR for B reads
    const int kqt = tid & 15;
    const int rbase = tid >> 4;

    const float* X = xs + (size_t)b * THW * CCH;

    float tv[4][TOPK];
    int   ti[4][TOPK];
#pragma unroll
    for (int j = 0; j < 4; ++j)
#pragma unroll
        for (int s = 0; s < TOPK; ++s) { tv[j][s] = -FLT_MAX; ti[j][s] = 0; }

    int fj[4];
#pragma unroll
    for (int j = 0; j < 4; ++j) fj[j] = (j0 + 4 * cg + j) / HW;

    for (int rt = 0; rt < THW / TR; ++rt) {
        const int t0 = rt * TR;
        float acc[8][4];
#pragma unroll
        for (int i = 0; i < 8; ++i)
#pragma unroll
            for (int j = 0; j < 4; ++j) acc[i][j] = 0.0f;

        for (int kc = 0; kc < CCH; kc += KC) {
            // stage A: 128 rows x 64 ch, XOR-swizzled quads
#pragma unroll
            for (int p = 0; p < 8; ++p) {
                const int r = rbase + 16 * p;
                const float4 v = *(const float4*)(X + (size_t)(t0 + r) * CCH + kc + 4 * kqt);
                *(float4*)(As + r * KC + 4 * (kqt ^ ((r >> 3) & 7))) = v;
            }
            // stage B: 64 cols x 64 ch
#pragma unroll
            for (int p = 0; p < 4; ++p) {
                const int r = rbase + 16 * p;
                const float4 v = *(const float4*)(X + (size_t)(j0 + r) * CCH + kc + 4 * kqt);
                *(float4*)(Bs + r * KC + 4 * (kqt ^ ((r >> 3) & 7))) = v;
            }
            __syncthreads();
            const float* pa = As + rg * (8 * KC);
            const float* pb = Bs + cg * (4 * KC);
#pragma unroll 4
            for (int m = 0; m < 16; ++m) {   // m = kq ^ swa  (A-linear order)
                float4 av[8];
#pragma unroll
                for (int i = 0; i < 8; ++i) av[i] = *(const float4*)(pa + i * KC + 4 * m);
                const float* pbm = (const float*)((const char*)pb + ((m << 4) ^ sab16));
                float4 bv[4];
#pragma unroll
                for (int j = 0; j < 4; ++j) bv[j] = *(const float4*)(pbm + j * KC);
#pragma unroll
                for (int i = 0; i < 8; ++i)
#pragma unroll
                    for (int j = 0; j < 4; ++j) {
                        acc[i][j] = fmaf(av[i].x, bv[j].x, acc[i][j]);
                        acc[i][j] = fmaf(av[i].y, bv[j].y, acc[i][j]);
                        acc[i][j] = fmaf(av[i].z, bv[j].z, acc[i][j]);
                        acc[i][j] = fmaf(av[i].w, bv[j].w, acc[i][j]);
                    }
            }
            __syncthreads();
        }
        // epilogue: scale by inv_nrm[t], mask same-frame, update private top-5
#pragma unroll
        for (int i = 0; i < 8; ++i) {
            const int t = t0 + 8 * rg + i;
            const float rv = rinv[b * THW + t];
            const int ft = t / HW;
#pragma unroll
            for (int j = 0; j < 4; ++j) {
                const float key = acc[i][j] * rv;
                if (ft != fj[j]) ins5(key, t, tv[j], ti[j]);
            }
        }
    }

    // cross-thread merge: 16 row-group owners x 5 entries per column
    __syncthreads();
    float* mv = smem;                       // [64][80] floats
    int*   mi = (int*)(smem + 64 * 80);     // [64][80] ints
#pragma unroll
    for (int j = 0; j < 4; ++j) {
        const int col = 4 * cg + j;
#pragma unroll
        for (int s = 0; s < TOPK; ++s) {
            mv[col * 80 + rg * TOPK + s] = tv[j][s];
            mi[col * 80 + rg * TOPK + s] = ti[j][s];
        }
    }
    __syncthreads();
    if (tid < TJ) {
        float bv5[TOPK]; int bi5[TOPK];
#pragma unroll
        for (int s = 0; s < TOPK; ++s) { bv5[s] = -FLT_MAX; bi5[s] = 0; }
        for (int s = 0; s < 80; ++s) ins5(mv[tid * 80 + s], mi[tid * 80 + s], bv5, bi5);
        int* op = idx5 + ((size_t)b * THW + j0 + tid) * TOPK;
#pragma unroll
        for (int s = 0; s < TOPK; ++s) op[s] = bi5[s];
    }
}

// ------------------------------------------------- 4. gather + max + BN partials
__global__ __launch_bounds__(256)
void gather_bn_kernel(const float* __restrict__ xs, const int* __restrict__ idx5,
                      float* __restrict__ y, float* __restrict__ partial) {
    __shared__ float ls[2][4][256];
    const int tid = threadIdx.x;
    const int wid = tid >> 6, lane = tid & 63;
    const int row0 = blockIdx.x * 32 + wid * 8;
    float s1x = 0, s1y = 0, s1z = 0, s1w = 0;
    float s2x = 0, s2y = 0, s2z = 0, s2w = 0;
    for (int rr = 0; rr < 8; ++rr) {
        const int row = row0 + rr;               // row = b*THW + j
        const int b = row / THW;
        const int* id = idx5 + (size_t)row * TOPK;
        const float* base = xs + (size_t)b * THW * CCH;
        float4 m = *(const float4*)(base + (size_t)id[0] * CCH + lane * 4);
#pragma unroll
        for (int i = 1; i < TOPK; ++i) {
            const float4 v = *(const float4*)(base + (size_t)id[i] * CCH + lane * 4);
            m.x = fmaxf(m.x, v.x); m.y = fmaxf(m.y, v.y);
            m.z = fmaxf(m.z, v.z); m.w = fmaxf(m.w, v.w);
        }
        *(float4*)(y + (size_t)row * CCH + lane * 4) = m;
        s1x += m.x; s1y += m.y; s1z += m.z; s1w += m.w;
        s2x += m.x * m.x; s2y += m.y * m.y; s2z += m.z * m.z; s2w += m.w * m.w;
    }
    *(float4*)&ls[0][wid][lane * 4] = make_float4(s1x, s1y, s1z, s1w);
    *(float4*)&ls[1][wid][lane * 4] = make_float4(s2x, s2y, s2z, s2w);
    __syncthreads();
    const float a  = ls[0][0][tid] + ls[0][1][tid] + ls[0][2][tid] + ls[0][3][tid];
    const float b2 = ls[1][0][tid] + ls[1][1][tid] + ls[1][2][tid] + ls[1][3][tid];
    partial[(size_t)blockIdx.x * 512 + tid] = a;
    partial[(size_t)blockIdx.x * 512 + 256 + tid] = b2;
}

// ------------------------------------------------- 5. BN finalize -> scale/shift
__global__ __launch_bounds__(256)
void bn_final_kernel(const float* __restrict__ partial, const float* __restrict__ gamma,
                     const float* __restrict__ beta, float* __restrict__ ab) {
    const int c = blockIdx.x;     // 256 blocks
    const int tid = threadIdx.x;
    float s1 = 0, s2 = 0;
    for (int p = tid; p < 784; p += 256) {
        s1 += partial[(size_t)p * 512 + c];
        s2 += partial[(size_t)p * 512 + 256 + c];
    }
    __shared__ float r1[256], r2[256];
    r1[tid] = s1; r2[tid] = s2;
    __syncthreads();
    for (int off = 128; off > 0; off >>= 1) {
        if (tid < off) { r1[tid] += r1[tid + off]; r2[tid] += r2[tid + off]; }
        __syncthreads();
    }
    if (tid == 0) {
        const float inv_n = 1.0f / 25088.0f;
        const float mean = r1[0] * inv_n;
        const float var  = r2[0] * inv_n - mean * mean;
        const float a = gamma[c] / sqrtf(var + 1e-5f);
        ab[c] = a;
        ab[256 + c] = beta[c] - mean * a;
    }
}

// ------------------------------------------------- 6. relu(BN) -> 1x1 conv + identity
__global__ __launch_bounds__(256, 2)
void conv_kernel(const float* __restrict__ y, const float* __restrict__ w,
                 const float* __restrict__ ab, const float* __restrict__ cb,
                 const float* __restrict__ x, float* __restrict__ out) {
    __shared__ float smem[(TR + TJ) * KC];
    float* As = smem;
    float* Bs = smem + TR * KC;
    const int tid = threadIdx.x;
    const int rt = blockIdx.x;         // 196 row tiles of 128
    const int o0 = blockIdx.y * TJ;    // 4 out-channel blocks
    const int rg = tid >> 4, cg = tid & 15;
    const int swa = rg & 7, swb = cg >> 1;
    const int sab16 = ((swa ^ swb) << 4);
    const int kqt = tid & 15, rbase = tid >> 4;

    float acc[8][4];
#pragma unroll
    for (int i = 0; i < 8; ++i)
#pragma unroll
        for (int j = 0; j < 4; ++j) acc[i][j] = 0.0f;

    for (int kc = 0; kc < CCH; kc += KC) {
        const int cbase = kc + 4 * kqt;
        const float4 sa = *(const float4*)(ab + cbase);
        const float4 sh = *(const float4*)(ab + 256 + cbase);
#pragma unroll
        for (int p = 0; p < 8; ++p) {
            const int r = rbase + 16 * p;
            const float4 v = *(const float4*)(y + (size_t)(rt * TR + r) * CCH + cbase);
            float4 z;
            z.x = fmaxf(fmaf(v.x, sa.x, sh.x), 0.0f);
            z.y = fmaxf(fmaf(v.y, sa.y, sh.y), 0.0f);
            z.z = fmaxf(fmaf(v.z, sa.z, sh.z), 0.0f);
            z.w = fmaxf(fmaf(v.w, sa.w, sh.w), 0.0f);
            *(float4*)(As + r * KC + 4 * (kqt ^ ((r >> 3) & 7))) = z;
        }
#pragma unroll
        for (int p = 0; p < 4; ++p) {
            const int r = rbase + 16 * p;
            const float4 v = *(const float4*)(w + (size_t)(o0 + r) * CCH + cbase);
            *(float4*)(Bs + r * KC + 4 * (kqt ^ ((r >> 3) & 7))) = v;
        }
        __syncthreads();
        const float* pa = As + rg * (8 * KC);
        const float* pb = Bs + cg * (4 * KC);
#pragma unroll 4
        for (int m = 0; m < 16; ++m) {
            float4 av[8];
#pragma unroll
            for (int i = 0; i < 8; ++i) av[i] = *(const float4*)(pa + i * KC + 4 * m);
            const float* pbm = (const float*)((const char*)pb + ((m << 4) ^ sab16));
            float4 bv[4];
#pragma unroll
            for (int j = 0; j < 4; ++j) bv[j] = *(const float4*)(pbm + j * KC);
#pragma unroll
            for (int i = 0; i < 8; ++i)
#pragma unroll
                for (int j = 0; j < 4; ++j) {
                    acc[i][j] = fmaf(av[i].x, bv[j].x, acc[i][j]);
                    acc[i][j] = fmaf(av[i].y, bv[j].y, acc[i][j]);
                    acc[i][j] = fmaf(av[i].z, bv[j].z, acc[i][j]);
                    acc[i][j] = fmaf(av[i].w, bv[j].w, acc[i][j]);
                }
        }
        __syncthreads();
    }
#pragma unroll
    for (int i = 0; i < 8; ++i) {
        const int R = rt * TR + 8 * rg + i;   // R = bs*HW + hw  (b-major rows)
        const int bs = R / HW;
        const int hw = R - bs * HW;
#pragma unroll
        for (int j = 0; j < 4; ++j) {
            const int o = o0 + 4 * cg + j;
            const size_t oi = ((size_t)bs * CCH + o) * HW + hw;
            out[oi] = acc[i][j] + cb[o] + x[oi];
        }
    }
}

// ------------------------------------------------- launch
extern "C" void kernel_launch(void* const* d_in, const int* in_sizes, int n_in,
                              void* d_out, int out_size, void* d_ws, size_t ws_size,
                              hipStream_t stream) {
    const float* x      = (const float*)d_in[0];
    const float* gamma  = (const float*)d_in[1];
    const float* beta   = (const float*)d_in[2];
    const float* conv_w = (const float*)d_in[3];
    const float* conv_b = (const float*)d_in[4];
    float* out = (float*)d_out;

    float* ws   = (float*)d_ws;
    float* xs   = ws;                     // 6422528 floats
    float* y    = ws + 6422528;           // 6422528 floats
    float* rinv = ws + 12845056;          // 25088
    float* part = ws + 12870144;          // 784*512 = 401408
    float* ab   = ws + 13271552;          // 512
    int*   idx5 = (int*)(ws + 13272064);  // 25088*5 ints  (total ~53.6 MB)

    transpose_kernel<<<dim3(32, 25, 8), 256, 0, stream>>>(x, xs);
    rownorm_kernel<<<6272, 256, 0, stream>>>(xs, rinv);
    gram_topk_kernel<<<dim3(THW / TJ, B_), 256, 0, stream>>>(xs, rinv, idx5);
    gather_bn_kernel<<<NROWS / 32, 256, 0, stream>>>(xs, idx5, y, part);
    bn_final_kernel<<<256, 256, 0, stream>>>(part, gamma, beta, ab);
    conv_kernel<<<dim3(NROWS / TR, CCH / TJ), 256, 0, stream>>>(y, conv_w, ab, conv_b, x, out);
}

// Round 2
// 583.328 us; speedup vs baseline: 3.7460x; 3.7460x over previous
//
#include <hip/hip_runtime.h>
#include <cfloat>

#define B_    4
#define SNIP  8
#define CCH   256
#define HW    784
#define THW   6272      // SNIP*HW
#define NROWS 25088     // B_*THW
#define TOPK  5

typedef _Float16 f16;
typedef f16   half8 __attribute__((ext_vector_type(8)));
typedef f16   half4 __attribute__((ext_vector_type(4)));
typedef float f32x4 __attribute__((ext_vector_type(4)));

// ---------------------------------------------------------------- utilities
__device__ __forceinline__ void ins5(float key, int idx, float tv[TOPK], int ti[TOPK]) {
    if (key > tv[4]) {
        if (key > tv[2]) {
            if (key > tv[1]) {
                tv[4] = tv[3]; ti[4] = ti[3];
                tv[3] = tv[2]; ti[3] = ti[2];
                tv[2] = tv[1]; ti[2] = ti[1];
                if (key > tv[0]) { tv[1] = tv[0]; ti[1] = ti[0]; tv[0] = key; ti[0] = idx; }
                else             { tv[1] = key;  ti[1] = idx; }
            } else {
                tv[4] = tv[3]; ti[4] = ti[3];
                tv[3] = tv[2]; ti[3] = ti[2];
                tv[2] = key;   ti[2] = idx;
            }
        } else {
            if (key > tv[3]) { tv[4] = tv[3]; ti[4] = ti[3]; tv[3] = key; ti[3] = idx; }
            else             { tv[4] = key;  ti[4] = idx; }
        }
    }
}

__device__ __forceinline__ void async16(const void* g, void* l) {
    __builtin_amdgcn_global_load_lds(
        (const __attribute__((address_space(1))) void*)g,
        (__attribute__((address_space(3))) void*)l, 16, 0, 0);
}

// ------------------------------------------------- 1. x[bs][c][p] -> xs[b][t][c]
__global__ __launch_bounds__(256)
void transpose_kernel(const float* __restrict__ x, float* __restrict__ xs) {
    __shared__ float T[32][33];
    const int bs = blockIdx.x;
    const int p0 = blockIdx.y * 32;
    const int c0 = blockIdx.z * 32;
    const int tx = threadIdx.x & 31, ty = threadIdx.x >> 5;
    const int b = bs >> 3, f = bs & 7;
#pragma unroll
    for (int q = 0; q < 4; ++q) {
        const int c = c0 + ty + 8 * q;
        const int p = p0 + tx;
        if (p < HW) T[ty + 8 * q][tx] = x[((size_t)bs * CCH + c) * HW + p];
    }
    __syncthreads();
#pragma unroll
    for (int q = 0; q < 4; ++q) {
        const int p = p0 + ty + 8 * q;
        if (p < HW)
            xs[((size_t)((size_t)b * THW + (size_t)f * HW + p)) * CCH + c0 + tx] = T[tx][ty + 8 * q];
    }
}

// ------------------------------------------------- 2. fp32 -> (hi,lo) f16 split
__global__ __launch_bounds__(256)
void split_kernel(const float* __restrict__ xs, f16* __restrict__ Xs) {
    const size_t i4 = ((size_t)blockIdx.x * 256 + threadIdx.x) * 4;
    const int row = (int)(i4 >> 8);
    const int c = (int)(i4 & 255);
    const float4 v = *(const float4*)(xs + i4);
    const f16 h0 = (f16)v.x, h1 = (f16)v.y, h2 = (f16)v.z, h3 = (f16)v.w;
    const f16 l0 = (f16)(v.x - (float)h0), l1 = (f16)(v.y - (float)h1);
    const f16 l2 = (f16)(v.z - (float)h2), l3 = (f16)(v.w - (float)h3);
    half4 hv; hv.x = h0; hv.y = h1; hv.z = h2; hv.w = h3;
    half4 lv; lv.x = l0; lv.y = l1; lv.z = l2; lv.w = l3;
    *(half4*)(Xs + (size_t)row * 512 + c) = hv;
    *(half4*)(Xs + (size_t)row * 512 + 256 + c) = lv;
}

// ------------------------------------------------- 3. per-row inverse norm
__global__ __launch_bounds__(256)
void rownorm_kernel(const float* __restrict__ xs, float* __restrict__ rinv) {
    const int tid = threadIdx.x;
    const int row = blockIdx.x * 4 + (tid >> 6);
    const int lane = tid & 63;
    const float4 v = *(const float4*)(xs + (size_t)row * CCH + lane * 4);
    float s = v.x * v.x + v.y * v.y + v.z * v.z + v.w * v.w;
#pragma unroll
    for (int m = 32; m >= 1; m >>= 1) s += __shfl_xor(s, m, 64);
    if (lane == 0) rinv[row] = 1.0f / sqrtf(s);
}

// ------------------------------------------------- 4. MFMA gram + partial top-5
// grid (49, 7, 4). Per block: 128-col block, 7 row-tiles of 128, virtual K=768
// (f16 split: segments A=[hi,lo,hi], B=[hi,hi,lo]).
__global__ __launch_bounds__(256, 2)
void gram_mfma_kernel(const f16* __restrict__ Xs, const float* __restrict__ rinv,
                      float* __restrict__ pval, int* __restrict__ pidx) {
    __shared__ char smem[40960];          // staging 32KB  |  merge 40KB (reused)
    f16* As = (f16*)smem;                 // [128][64] halves, unit-swizzled
    f16* Bs = As + 8192;

    const int tid = threadIdx.x;
    const int lane = tid & 63, wid = tid >> 6;
    const int wr = (wid >> 1) * 64, wc = (wid & 1) * 64;
    const int lm = lane & 15, q = lane >> 4;
    const int lm7 = lm & 7;
    const int b = blockIdx.z;
    const int j0 = blockIdx.x * 128;
    const int rg = blockIdx.y;
    const size_t bbase = (size_t)b * THW;
    const f16* Xb = Xs + bbase * 512;
    const float* rv = rinv + bbase;

    // staging lane map: row within pass, swizzled 16B-unit within row
    const int srow = tid >> 3;
    const int skk = (((tid & 7) ^ (srow & 7)) * 8);   // halves

    int fj[4];
#pragma unroll
    for (int j = 0; j < 4; ++j) fj[j] = (j0 + wc + 16 * j + lm) / HW;

    float tv[4][TOPK];
    int   ti[4][TOPK];
#pragma unroll
    for (int j = 0; j < 4; ++j)
#pragma unroll
        for (int s = 0; s < TOPK; ++s) { tv[j][s] = -FLT_MAX; ti[j][s] = 0; }

    const int segA[3] = {0, 256, 0};
    const int segB[3] = {0, 0, 256};

    for (int it = 0; it < 7; ++it) {
        const int t0 = (rg * 7 + it) * 128;
        f32x4 acc[4][4];
#pragma unroll
        for (int i = 0; i < 4; ++i)
#pragma unroll
            for (int j = 0; j < 4; ++j) acc[i][j] = (f32x4)0.0f;

        for (int cc = 0; cc < 12; ++cc) {
            const int seg = cc >> 2, k64 = (cc & 3) * 64;
            const int aoff = segA[seg] + k64 + skk;
            const int boff = segB[seg] + k64 + skk;
#pragma unroll
            for (int p = 0; p < 4; ++p)
                async16(Xb + (size_t)(t0 + srow + 32 * p) * 512 + aoff,
                        smem + wid * 1024 + p * 4096);
#pragma unroll
            for (int p = 0; p < 4; ++p)
                async16(Xb + (size_t)(j0 + srow + 32 * p) * 512 + boff,
                        smem + 16384 + wid * 1024 + p * 4096);
            __syncthreads();
#pragma unroll
            for (int ks = 0; ks < 2; ++ks) {
                const int ku = (((4 * ks + q) ^ lm7) * 8);   // swizzled unit, halves
                half8 av[4], bv[4];
#pragma unroll
                for (int i = 0; i < 4; ++i)
                    av[i] = *(const half8*)(As + (wr + 16 * i + lm) * 64 + ku);
#pragma unroll
                for (int j = 0; j < 4; ++j)
                    bv[j] = *(const half8*)(Bs + (wc + 16 * j + lm) * 64 + ku);
#pragma unroll
                for (int i = 0; i < 4; ++i)
#pragma unroll
                    for (int j = 0; j < 4; ++j)
                        acc[i][j] = __builtin_amdgcn_mfma_f32_16x16x32_f16(av[i], bv[j], acc[i][j], 0, 0, 0);
            }
            __syncthreads();
        }
        // epilogue: key = up * rinv[row]; mask same-frame; private top-5
#pragma unroll
        for (int i = 0; i < 4; ++i) {
            const int tb = t0 + wr + 16 * i + 4 * q;
            const f32x4 r4 = *(const f32x4*)(rv + tb);
#pragma unroll
            for (int reg = 0; reg < 4; ++reg) {
                const int t = tb + reg;
                const int ft = t / HW;
#pragma unroll
                for (int j = 0; j < 4; ++j) {
                    const float key = acc[i][j][reg] * r4[reg];
                    if (ft != fj[j]) ins5(key, t, tv[j], ti[j]);
                }
            }
        }
    }

    // merge: per column (128), 8 contributor slots (2 waves x 4 q) x 5 entries
    __syncthreads();
    float* Mv = (float*)smem;                  // 128*8*5 = 5120 floats (20KB)
    int*   Mi = (int*)(smem + 20480);
    const int slot = (wid >> 1) * 4 + q;
#pragma unroll
    for (int j = 0; j < 4; ++j) {
        const int c128 = wc + 16 * j + lm;
#pragma unroll
        for (int s = 0; s < TOPK; ++s) {
            Mv[(c128 * 8 + slot) * TOPK + s] = tv[j][s];
            Mi[(c128 * 8 + slot) * TOPK + s] = ti[j][s];
        }
    }
    __syncthreads();
    if (tid < 128) {
        float bv5[TOPK]; int bi5[TOPK];
#pragma unroll
        for (int s = 0; s < TOPK; ++s) { bv5[s] = -FLT_MAX; bi5[s] = 0; }
        for (int s = 0; s < 40; ++s) ins5(Mv[tid * 40 + s], Mi[tid * 40 + s], bv5, bi5);
        const size_t base = ((bbase + j0 + tid) * 7 + rg) * TOPK;
#pragma unroll
        for (int s = 0; s < TOPK; ++s) { pval[base + s] = bv5[s]; pidx[base + s] = bi5[s]; }
    }
}

// ------------------------------------------------- 5. merge row-group partials
__global__ __launch_bounds__(256)
void merge_topk_kernel(const float* __restrict__ pval, const int* __restrict__ pidx,
                       int* __restrict__ idx5) {
    const int gid = blockIdx.x * 256 + threadIdx.x;   // 25088 columns
    float bv5[TOPK]; int bi5[TOPK];
#pragma unroll
    for (int s = 0; s < TOPK; ++s) { bv5[s] = -FLT_MAX; bi5[s] = 0; }
    const float* pv = pval + (size_t)gid * 35;
    const int* pi = pidx + (size_t)gid * 35;
    for (int s = 0; s < 35; ++s) ins5(pv[s], pi[s], bv5, bi5);
    int* op = idx5 + (size_t)gid * TOPK;
#pragma unroll
    for (int s = 0; s < TOPK; ++s) op[s] = bi5[s];
}

// ------------------------------------------------- 6. gather + max + BN partials
__global__ __launch_bounds__(256)
void gather_bn_kernel(const float* __restrict__ xs, const int* __restrict__ idx5,
                      float* __restrict__ y, float* __restrict__ partial) {
    __shared__ float ls[2][4][256];
    const int tid = threadIdx.x;
    const int wid = tid >> 6, lane = tid & 63;
    const int row0 = blockIdx.x * 32 + wid * 8;
    float s1x = 0, s1y = 0, s1z = 0, s1w = 0;
    float s2x = 0, s2y = 0, s2z = 0, s2w = 0;
    for (int rr = 0; rr < 8; ++rr) {
        const int row = row0 + rr;
        const int b = row / THW;
        const int* id = idx5 + (size_t)row * TOPK;
        const float* base = xs + (size_t)b * THW * CCH;
        float4 m = *(const float4*)(base + (size_t)id[0] * CCH + lane * 4);
#pragma unroll
        for (int i = 1; i < TOPK; ++i) {
            const float4 v = *(const float4*)(base + (size_t)id[i] * CCH + lane * 4);
            m.x = fmaxf(m.x, v.x); m.y = fmaxf(m.y, v.y);
            m.z = fmaxf(m.z, v.z); m.w = fmaxf(m.w, v.w);
        }
        *(float4*)(y + (size_t)row * CCH + lane * 4) = m;
        s1x += m.x; s1y += m.y; s1z += m.z; s1w += m.w;
        s2x += m.x * m.x; s2y += m.y * m.y; s2z += m.z * m.z; s2w += m.w * m.w;
    }
    *(float4*)&ls[0][wid][lane * 4] = make_float4(s1x, s1y, s1z, s1w);
    *(float4*)&ls[1][wid][lane * 4] = make_float4(s2x, s2y, s2z, s2w);
    __syncthreads();
    const float a  = ls[0][0][tid] + ls[0][1][tid] + ls[0][2][tid] + ls[0][3][tid];
    const float b2 = ls[1][0][tid] + ls[1][1][tid] + ls[1][2][tid] + ls[1][3][tid];
    partial[(size_t)blockIdx.x * 512 + tid] = a;
    partial[(size_t)blockIdx.x * 512 + 256 + tid] = b2;
}

// ------------------------------------------------- 7. BN finalize -> scale/shift
__global__ __launch_bounds__(256)
void bn_final_kernel(const float* __restrict__ partial, const float* __restrict__ gamma,
                     const float* __restrict__ beta, float* __restrict__ ab) {
    const int c = blockIdx.x;
    const int tid = threadIdx.x;
    float s1 = 0, s2 = 0;
    for (int p = tid; p < 784; p += 256) {
        s1 += partial[(size_t)p * 512 + c];
        s2 += partial[(size_t)p * 512 + 256 + c];
    }
    __shared__ float r1[256], r2[256];
    r1[tid] = s1; r2[tid] = s2;
    __syncthreads();
    for (int off = 128; off > 0; off >>= 1) {
        if (tid < off) { r1[tid] += r1[tid + off]; r2[tid] += r2[tid + off]; }
        __syncthreads();
    }
    if (tid == 0) {
        const float inv_n = 1.0f / 25088.0f;
        const float mean = r1[0] * inv_n;
        const float var  = r2[0] * inv_n - mean * mean;
        const float a = gamma[c] / sqrtf(var + 1e-5f);
        ab[c] = a;
        ab[256 + c] = beta[c] - mean * a;
    }
}

// ------------------------------------------------- 8. relu(BN) -> 1x1 conv + identity
#define TR 128
#define TJ 64
#define KC 64
__global__ __launch_bounds__(256, 2)
void conv_kernel(const float* __restrict__ y, const float* __restrict__ w,
                 const float* __restrict__ ab, const float* __restrict__ cb,
                 const float* __restrict__ x, float* __restrict__ out) {
    __shared__ float smem[(TR + TJ) * KC];
    float* As = smem;
    float* Bs = smem + TR * KC;
    const int tid = threadIdx.x;
    const int rt = blockIdx.x;
    const int o0 = blockIdx.y * TJ;
    const int rg = tid >> 4, cg = tid & 15;
    const int swa = rg & 7, swb = cg >> 1;
    const int sab16 = ((swa ^ swb) << 4);
    const int kqt = tid & 15, rbase = tid >> 4;

    float acc[8][4];
#pragma unroll
    for (int i = 0; i < 8; ++i)
#pragma unroll
        for (int j = 0; j < 4; ++j) acc[i][j] = 0.0f;

    for (int kc = 0; kc < CCH; kc += KC) {
        const int cbase = kc + 4 * kqt;
        const float4 sa = *(const float4*)(ab + cbase);
        const float4 sh = *(const float4*)(ab + 256 + cbase);
#pragma unroll
        for (int p = 0; p < 8; ++p) {
            const int r = rbase + 16 * p;
            const float4 v = *(const float4*)(y + (size_t)(rt * TR + r) * CCH + cbase);
            float4 z;
            z.x = fmaxf(fmaf(v.x, sa.x, sh.x), 0.0f);
            z.y = fmaxf(fmaf(v.y, sa.y, sh.y), 0.0f);
            z.z = fmaxf(fmaf(v.z, sa.z, sh.z), 0.0f);
            z.w = fmaxf(fmaf(v.w, sa.w, sh.w), 0.0f);
            *(float4*)(As + r * KC + 4 * (kqt ^ ((r >> 3) & 7))) = z;
        }
#pragma unroll
        for (int p = 0; p < 4; ++p) {
            const int r = rbase + 16 * p;
            const float4 v = *(const float4*)(w + (size_t)(o0 + r) * CCH + cbase);
            *(float4*)(Bs + r * KC + 4 * (kqt ^ ((r >> 3) & 7))) = v;
        }
        __syncthreads();
        const float* pa = As + rg * (8 * KC);
        const float* pb = Bs + cg * (4 * KC);
#pragma unroll 4
        for (int m = 0; m < 16; ++m) {
            float4 av[8];
#pragma unroll
            for (int i = 0; i < 8; ++i) av[i] = *(const float4*)(pa + i * KC + 4 * m);
            const float* pbm = (const float*)((const char*)pb + ((m << 4) ^ sab16));
            float4 bv[4];
#pragma unroll
            for (int j = 0; j < 4; ++j) bv[j] = *(const float4*)(pbm + j * KC);
#pragma unroll
            for (int i = 0; i < 8; ++i)
#pragma unroll
                for (int j = 0; j < 4; ++j) {
                    acc[i][j] = fmaf(av[i].x, bv[j].x, acc[i][j]);
                    acc[i][j] = fmaf(av[i].y, bv[j].y, acc[i][j]);
                    acc[i][j] = fmaf(av[i].z, bv[j].z, acc[i][j]);
                    acc[i][j] = fmaf(av[i].w, bv[j].w, acc[i][j]);
                }
        }
        __syncthreads();
    }
#pragma unroll
    for (int i = 0; i < 8; ++i) {
        const int R = rt * TR + 8 * rg + i;
        const int bs = R / HW;
        const int hw = R - bs * HW;
#pragma unroll
        for (int j = 0; j < 4; ++j) {
            const int o = o0 + 4 * cg + j;
            const size_t oi = ((size_t)bs * CCH + o) * HW + hw;
            out[oi] = acc[i][j] + cb[o] + x[oi];
        }
    }
}

// ------------------------------------------------- launch
extern "C" void kernel_launch(void* const* d_in, const int* in_sizes, int n_in,
                              void* d_out, int out_size, void* d_ws, size_t ws_size,
                              hipStream_t stream) {
    const float* x      = (const float*)d_in[0];
    const float* gamma  = (const float*)d_in[1];
    const float* beta   = (const float*)d_in[2];
    const float* conv_w = (const float*)d_in[3];
    const float* conv_b = (const float*)d_in[4];
    float* out = (float*)d_out;

    float* ws   = (float*)d_ws;
    float* xs   = ws;                        // 6,422,528 floats
    f16*   Xsp  = (f16*)(ws + 6422528);      // 12,845,056 halves (25.7MB) -- reused as y
    float* y    = ws + 6422528;              // union with Xsp (Xsp dead before gather)
    float* rinv = ws + 12845056;             // 25,088
    float* part = ws + 12870144;             // 401,408
    float* ab   = ws + 13271552;             // 512
    int*   idx5 = (int*)(ws + 13272064);     // 125,440 ints
    float* pval = ws + 13397504;             // 878,080
    int*   pidx = (int*)(ws + 14275584);     // 878,080 ints   (total ~60.6 MB)

    transpose_kernel<<<dim3(32, 25, 8), 256, 0, stream>>>(x, xs);
    split_kernel<<<6272, 256, 0, stream>>>(xs, Xsp);
    rownorm_kernel<<<6272, 256, 0, stream>>>(xs, rinv);
    gram_mfma_kernel<<<dim3(49, 7, 4), 256, 0, stream>>>(Xsp, rinv, pval, pidx);
    merge_topk_kernel<<<98, 256, 0, stream>>>(pval, pidx, idx5);
    gather_bn_kernel<<<NROWS / 32, 256, 0, stream>>>(xs, idx5, y, part);
    bn_final_kernel<<<256, 256, 0, stream>>>(part, gamma, beta, ab);
    conv_kernel<<<dim3(NROWS / TR, CCH / TJ), 256, 0, stream>>>(y, conv_w, ab, conv_b, x, out);
}